// Round 11
// baseline (155.434 us; speedup 1.0000x reference)
//
#include <hip/hip_runtime.h>

// B=2, S=2048, D_IN=1024, H=16, HD=64 causal MHA. fp32 I/O, bf16 MFMA inside.
// prep_k (x->bf16 + W->Wt merged) ;
// proj_k (fused QKV GEMM, 128x192 tile, dbuf XOR-swizzled LDS) ;
// attn_k (r11: single q-tile/block, t-tile 64, 40KB LDS -> 4 blocks/CU,
//   1024 blocks heavy-first, dbuf K/V staging, swizzled LDS, no shuffles).

#define DI   1024
#define HD   64
#define NH   16
#define SEQ  2048
#define NB   2

typedef unsigned short u16;
typedef unsigned short us8 __attribute__((ext_vector_type(8)));
typedef unsigned short us4 __attribute__((ext_vector_type(4)));
typedef unsigned int   u32x2 __attribute__((ext_vector_type(2)));
typedef short bf8 __attribute__((ext_vector_type(8)));   // 8 x bf16
typedef float f4 __attribute__((ext_vector_type(4)));

#define MFMA16(a, b, c) __builtin_amdgcn_mfma_f32_16x16x32_bf16((a), (b), (c), 0, 0, 0)

#if __has_builtin(__builtin_amdgcn_exp2f)
#define EXP2(x) __builtin_amdgcn_exp2f(x)
#else
#define EXP2(x) exp2f(x)
#endif

#if __has_builtin(__builtin_amdgcn_perm)
#define PKHI(a, b) __builtin_amdgcn_perm((a), (b), 0x07060302u)
#else
__device__ __forceinline__ unsigned PKHI(unsigned a, unsigned b) {
  return (b >> 16) | (a & 0xffff0000u);
}
#endif

__device__ __forceinline__ u16 f2bf(float f) {  // RNE fp32 -> bf16
  unsigned u = __float_as_uint(f);
  u += 0x7fffu + ((u >> 16) & 1u);
  return (u16)(u >> 16);
}

// async global->LDS, 16B/lane; LDS dest = wave-uniform base + lane*16.
__device__ __forceinline__ void async16(const u16* g, u16* l) {
  __builtin_amdgcn_global_load_lds((const __attribute__((address_space(1))) void*)g,
                                   (__attribute__((address_space(3))) void*)l,
                                   16, 0, 0);
}

// ------------- prep: x fp32->bf16 (grid.x<2048) + W transpose (>=2048) -----
__global__ __launch_bounds__(256) void prep_k(const float* __restrict__ x,
                                              const float* __restrict__ Wq,
                                              const float* __restrict__ Wk,
                                              const float* __restrict__ Wv,
                                              u16* __restrict__ xb,
                                              u16* __restrict__ Wt) {
  __shared__ __align__(16) u16 tile[64][72];
  const int bid = blockIdx.x;
  if (bid < 2048) {                              // ---- x conversion ----
    const int i = (bid * 256 + threadIdx.x) * 8;
    float4 v0 = *(const float4*)(x + i);
    float4 v1 = *(const float4*)(x + i + 4);
    us8 o;
    o[0] = f2bf(v0.x); o[1] = f2bf(v0.y); o[2] = f2bf(v0.z); o[3] = f2bf(v0.w);
    o[4] = f2bf(v1.x); o[5] = f2bf(v1.y); o[6] = f2bf(v1.z); o[7] = f2bf(v1.w);
    *(us8*)(xb + i) = o;
    return;
  }
  const int idx = bid - 2048;                    // ---- W transpose ----
  const int mh = idx >> 4;
  const int d0 = (idx & 15) * 64;
  const int mat = mh >> 4, h = mh & 15;
  const float* W = (mat == 0 ? Wq : (mat == 1 ? Wk : Wv)) + (size_t)h * DI * HD;
  const int t = threadIdx.x;
  {
    const int r = t >> 2, c = (t & 3) * 16;
    const float* src = W + (size_t)(d0 + r) * HD + c;
    #pragma unroll
    for (int j = 0; j < 4; j++) {
      float4 v = *(const float4*)(src + j * 4);
      tile[r][c + j * 4 + 0] = f2bf(v.x);
      tile[r][c + j * 4 + 1] = f2bf(v.y);
      tile[r][c + j * 4 + 2] = f2bf(v.z);
      tile[r][c + j * 4 + 3] = f2bf(v.w);
    }
  }
  __syncthreads();
  {
    const int e = t >> 2, c = (t & 3) * 16;
    __align__(16) u16 tmp[16];
    #pragma unroll
    for (int i = 0; i < 16; i++) tmp[i] = tile[c + i][e];
    u16* dst = Wt + ((size_t)mh * HD + e) * DI + d0 + c;
    *(us8*)dst       = *(us8*)&tmp[0];
    *(us8*)(dst + 8) = *(us8*)&tmp[8];
  }
}

// ---------------- fused QKV GEMM: [4096x1024] x [1024x3072] ----------------
// (unchanged from round 10: 128x192 tile, dbuf, XOR-swizzled)
__global__ __launch_bounds__(256, 2) void proj_k(const u16* __restrict__ x,
                                                 const u16* __restrict__ Wt,
                                                 u16* __restrict__ Qo,
                                                 u16* __restrict__ Ko,
                                                 u16* __restrict__ Vo) {
  __shared__ __align__(16) u16 smem[40960];      // xs 2x8192 | ws 2x12288
  u16* const xs = smem;
  u16* const ws = smem + 16384;
  const int m0 = blockIdx.x * 128, n0 = blockIdx.y * 192;
  const int tid = threadIdx.x, w = tid >> 6, lane = tid & 63;
  const int l15 = lane & 15, quad = lane >> 4, l7 = l15 & 7;
  const int lrow = lane >> 3, lch = lane & 7;
  const int wm = w >> 1, wn = w & 1;

  f4 acc[4][6];
  #pragma unroll
  for (int i = 0; i < 4; i++)
    #pragma unroll
    for (int j = 0; j < 6; j++) {
      f4 z = {0.f, 0.f, 0.f, 0.f};
      acc[i][j] = z;
    }

  const u16* xg = x  + (size_t)(m0 + lrow) * DI + ((lch ^ lrow) * 8);
  const u16* wg = Wt + (size_t)(n0 + lrow) * DI + ((lch ^ lrow) * 8);

  #pragma unroll
  for (int i = 0; i < 4; i++)
    async16(xg + (size_t)(i * 32 + w * 8) * DI, &xs[(i * 32 + w * 8) * 64]);
  #pragma unroll
  for (int c = 0; c < 6; c++)
    async16(wg + (size_t)(w * 48 + c * 8) * DI, &ws[(w * 48 + c * 8) * 64]);

  for (int it = 0; it < 16; it++) {
    const int cbx = (it & 1) * 8192, cbw = (it & 1) * 12288;
    __syncthreads();
    if (it + 1 < 16) {
      const int k1 = (it + 1) * 64;
      const int nbx = 8192 - cbx, nbw = 12288 - cbw;
      #pragma unroll
      for (int i = 0; i < 4; i++)
        async16(xg + (size_t)(i * 32 + w * 8) * DI + k1,
                &xs[nbx + (i * 32 + w * 8) * 64]);
      #pragma unroll
      for (int c = 0; c < 6; c++)
        async16(wg + (size_t)(w * 48 + c * 8) * DI + k1,
                &ws[nbw + (w * 48 + c * 8) * 64]);
    }
    #pragma unroll
    for (int ks = 0; ks < 64; ks += 32) {
      const int c0 = (ks >> 3) + quad;
      bf8 af[4], bfr[6];
      #pragma unroll
      for (int i = 0; i < 4; i++)
        af[i] = *(const bf8*)&xs[cbx + (wm * 64 + i * 16 + l15) * 64 + ((c0 ^ l7) * 8)];
      #pragma unroll
      for (int i = 0; i < 6; i++)
        bfr[i] = *(const bf8*)&ws[cbw + (wn * 96 + i * 16 + l15) * 64 + ((c0 ^ l7) * 8)];
      #pragma unroll
      for (int mi = 0; mi < 4; mi++)
        #pragma unroll
        for (int ni = 0; ni < 6; ni++)
          acc[mi][ni] = MFMA16(af[mi], bfr[ni], acc[mi][ni]);
    }
  }

  const float qscale = 0.125f * 1.44269504088896340736f;
  #pragma unroll
  for (int mi = 0; mi < 4; mi++) {
    const int mrow = m0 + wm * 64 + mi * 16 + quad * 4;
    const int b = mrow >> 11, sb = mrow & (SEQ - 1);
    #pragma unroll
    for (int ni = 0; ni < 6; ni++) {
      const int nf = n0 + wn * 96 + ni * 16;
      const int mat = nf >> 10;
      const int h = (nf >> 6) & 15;
      const int e = (nf & 63) + l15;
      if (mat == 2) {
        __align__(8) u16 pk[4];
        #pragma unroll
        for (int r = 0; r < 4; r++) pk[r] = f2bf(acc[mi][ni][r]);
        *(us4*)(Vo + (((size_t)b * NH + h) * HD + e) * SEQ + sb) = *(us4*)pk;
      } else {
        u16* O = mat ? Ko : Qo;
        const float sc = mat ? 1.0f : qscale;
        #pragma unroll
        for (int r = 0; r < 4; r++)
          O[(((size_t)b * NH + h) * SEQ + sb + r) * HD + e] = f2bf(acc[mi][ni][r] * sc);
      }
    }
  }
}

// ------- flash attention: single q-tile/block, t-tile 64, 4 blocks/CU ------
// grid (32 qtiles heavy-first, 32 bh) = 1024 blocks; 4 waves; wave w owns
// q rows [qt*64+w*16, +16). LDS 40KB: K dbuf 16K | V dbuf 16K | Ps 8K.
__global__ __launch_bounds__(256, 4) void attn_k(const u16* __restrict__ Qo,
                                                 const u16* __restrict__ Ko,
                                                 const u16* __restrict__ Vo,
                                                 float* __restrict__ out) {
  __shared__ __align__(16) u16 Ks[2 * 64 * 64];    // [buf][t][e], swizzled
  __shared__ __align__(16) u16 Vs[2 * 64 * 64];    // [buf][e][t], swizzled
  __shared__ __align__(16) u16 Ps[4 * 16 * 64];    // per-wave [q][t], swizzled
  const int qt = 31 - (int)blockIdx.x;             // heavy tiles first
  const int bh = blockIdx.y;
  const int b = bh >> 4, h = bh & 15;
  const int tid = threadIdx.x, w = tid >> 6, lane = tid & 63;
  const int l15 = lane & 15, quad = lane >> 4, l7 = l15 & 7;
  const int qh = quad >> 1, ql = quad & 1;

  const u16* Qb = Qo + (size_t)bh * SEQ * HD;
  const u16* Kb = Ko + (size_t)bh * SEQ * HD;
  const u16* Vb = Vo + (size_t)bh * HD * SEQ;

  const int qrow = qt * 64 + w * 16 + l15;
  bf8 bq0 = *(const bf8*)(Qb + (size_t)qrow * HD + quad * 8);
  bf8 bq1 = *(const bf8*)(Qb + (size_t)qrow * HD + 32 + quad * 8);

  f4 oacc[4], lacc;
  #pragma unroll
  for (int i = 0; i < 4; i++) {
    f4 z = {0.f, 0.f, 0.f, 0.f};
    oacc[i] = z;
  }
  {
    f4 z = {0.f, 0.f, 0.f, 0.f};
    lacc = z;
  }
  const bf8 ones = {0x3F80, 0x3F80, 0x3F80, 0x3F80, 0x3F80, 0x3F80, 0x3F80, 0x3F80};

  const int niter = qt + 1;

  // ---- loop-invariant LDS frag pointers (buffer 0; +4096 u16 for buf 1) ----
  const u16* ksp0 = &Ks[l15 * 64 + ((quad ^ l7) * 8)];          // +mf*1024
  const u16* ksp1 = &Ks[l15 * 64 + (((quad + 4) ^ l7) * 8)];
  const u16* vsp[2];
  #pragma unroll
  for (int tc = 0; tc < 2; tc++)
    vsp[tc] = &Vs[l15 * 64 + (((tc * 4 + quad) ^ l7) * 8)];     // +ef*1024
  u16* const psw = &Ps[w * 1024 + l15 * 64 + ql * 4];           // +slot*8
  const u16* prp[2];
  #pragma unroll
  for (int tc = 0; tc < 2; tc++)
    prp[tc] = &Ps[w * 1024 + l15 * 64 + (((tc * 4 + quad) ^ l7) * 8)];

  // ---- staging: wave w covers rows [w*16, w*16+16), 2 calls of 8 rows ----
  const int kl = lane >> 3, kc = lane & 7;
  const int sw = (kc ^ kl) * 8;
  const u16* kg = Kb + (size_t)(w * 16 + kl) * HD + sw;         // +8*HD, +64*HD/it
  const u16* vg = Vb + (size_t)(w * 16 + kl) * SEQ + sw;        // +8*SEQ, +64/it
  u16* const ldsK = &Ks[(w * 16) * 64];                         // +512, +buf*4096
  u16* const ldsV = &Vs[(w * 16) * 64];

  const int mq = qrow - qt * 64 - quad * 4;        // mask if mf*16+r > mq (last)

  // prologue: stage tile 0 into buffer 0
  async16(kg, ldsK);
  async16(kg + 8 * HD, ldsK + 512);
  async16(vg, ldsV);
  async16(vg + 8 * SEQ, ldsV + 512);
  kg += 64 * HD; vg += 64;

  for (int it = 0; it < niter; it++) {
    const int cb = (it & 1) * 4096;
    __syncthreads();                               // drain this iter's staging
    if (it + 1 < niter) {                          // prefetch next into other buf
      const int nb = 4096 - cb;
      async16(kg, ldsK + nb);
      async16(kg + 8 * HD, ldsK + nb + 512);
      async16(vg, ldsV + nb);
      async16(vg + 8 * SEQ, ldsV + nb + 512);
      kg += 64 * HD; vg += 64;
    }

    // S^T = K·Q^T (exp2 domain; scale folded into Q)
    f4 s[4];
    #pragma unroll
    for (int mf = 0; mf < 4; mf++) {
      bf8 ak0 = *(const bf8*)(ksp0 + cb + mf * 1024);
      bf8 ak1 = *(const bf8*)(ksp1 + cb + mf * 1024);
      f4 z = {0.f, 0.f, 0.f, 0.f};
      f4 t = MFMA16(ak0, bq0, z);
      s[mf] = MFMA16(ak1, bq1, t);
    }

    // P phase: mask (last iter) -> exp2 -> truncate-pack -> swizzled write
    const bool domask = (it == niter - 1);
    #pragma unroll
    for (int mf = 0; mf < 4; mf++) {
      f4 sv = s[mf];
      if (domask) {
        #pragma unroll
        for (int r = 0; r < 4; r++)
          sv[r] = (mf * 16 + r <= mq) ? sv[r] : -1e30f;
      }
      const unsigned p0 = __float_as_uint(EXP2(sv[0]));
      const unsigned p1 = __float_as_uint(EXP2(sv[1]));
      const unsigned p2 = __float_as_uint(EXP2(sv[2]));
      const unsigned p3 = __float_as_uint(EXP2(sv[3]));
      u32x2 pk = {PKHI(p1, p0), PKHI(p3, p2)};
      *(u32x2*)(psw + (((mf * 2 + qh) ^ l7) * 8)) = pk;
    }

    // O^T += V^T·P^T (+ row-sum via ones-MFMA)
    #pragma unroll
    for (int tc = 0; tc < 2; tc++) {
      bf8 pf = *(const bf8*)(prp[tc]);
      lacc = MFMA16(ones, pf, lacc);
      #pragma unroll
      for (int ef = 0; ef < 4; ef++) {
        bf8 vf = *(const bf8*)(vsp[tc] + cb + ef * 1024);
        oacc[ef] = MFMA16(vf, pf, oacc[ef]);
      }
    }
  }

  const float inv = 1.0f / lacc[0];
  float* op = out + ((size_t)b * SEQ + qrow) * (NH * HD) + h * HD + quad * 4;
  #pragma unroll
  for (int ef = 0; ef < 4; ef++) {
    f4 v = oacc[ef] * inv;
    *(float4*)(op + ef * 16) = *(float4*)&v;
  }
}

extern "C" void kernel_launch(void* const* d_in, const int* in_sizes, int n_in,
                              void* d_out, int out_size, void* d_ws, size_t ws_size,
                              hipStream_t stream) {
  const float* x  = (const float*)d_in[0];
  const float* Wq = (const float*)d_in[1];
  const float* Wk = (const float*)d_in[2];
  const float* Wv = (const float*)d_in[3];
  float* out = (float*)d_out;

  u16* xb = (u16*)d_ws;
  u16* Wt = xb + (size_t)NB * SEQ * DI;
  u16* Qo = Wt + (size_t)3 * NH * HD * DI;
  u16* Ko = Qo + (size_t)NB * NH * SEQ * HD;
  u16* Vo = Ko + (size_t)NB * NH * SEQ * HD;

  prep_k<<<dim3(2048 + 768), 256, 0, stream>>>(x, Wq, Wk, Wv, xb, Wt);
  proj_k<<<dim3(32, 16), 256, 0, stream>>>(xb, Wt, Qo, Ko, Vo);
  attn_k<<<dim3(32, 32), 256, 0, stream>>>(Qo, Ko, Vo, out);
}